// Round 9
// baseline (218.118 us; speedup 1.0000x reference)
//
#include <hip/hip_runtime.h>

// 1 - alpha = (1 + exp(density+shift))^(-0.5) = rsqrt(u), u = 1 + exp(x).
// w_k = T_excl * alpha_k,  T_excl accumulated as product of (1-alpha).

__device__ __forceinline__ float fast_sigmoid(float x) {
    return __builtin_amdgcn_rcpf(1.0f + __expf(-x));
}

struct __align__(4) f3  { float x, y, z; };     // 12B, 4B-aligned
struct __align__(4) f4s { float x, y, z, w; };  // 16B, 4B-aligned -> dwordx4

// ---- DPP wave64 scans ------------------------------------------------------
#define DPP_ADD(x, ctrl, rmask)                                               \
    do {                                                                      \
        int _s = __builtin_amdgcn_update_dpp(0, __float_as_int(x), (ctrl),    \
                                             (rmask), 0xf, true);             \
        (x) += __int_as_float(_s);                                            \
    } while (0)

#define DPP_MUL(x, ctrl, rmask)                                               \
    do {                                                                      \
        int _s = __builtin_amdgcn_update_dpp(0x3f800000, __float_as_int(x),   \
                                             (ctrl), (rmask), 0xf, false);    \
        (x) *= __int_as_float(_s);                                            \
    } while (0)

// Inclusive scans SEGMENTED at the lane-31/32 boundary (R3/R8-verified).
__device__ __forceinline__ float half_scan_mul(float x) {
    DPP_MUL(x, 0x111, 0xf);
    DPP_MUL(x, 0x112, 0xf);
    DPP_MUL(x, 0x114, 0xf);
    DPP_MUL(x, 0x118, 0xf);
    DPP_MUL(x, 0x142, 0xa);
    return x;
}
__device__ __forceinline__ float half_scan_add(float x) {
    DPP_ADD(x, 0x111, 0xf);
    DPP_ADD(x, 0x112, 0xf);
    DPP_ADD(x, 0x114, 0xf);
    DPP_ADD(x, 0x118, 0xf);
    DPP_ADD(x, 0x142, 0xa);
    return x;
}

__device__ __forceinline__ float bperm_f(int lane, float v) {
    return __int_as_float(
        __builtin_amdgcn_ds_bpermute(lane * 4, __float_as_int(v)));
}
__device__ __forceinline__ int rdlane(int v, int l) {
    return __builtin_amdgcn_readlane(v, l);
}

// ---- Pass 1: segment starts (int4-vectorized boundary detection) -----------
__global__ __launch_bounds__(256) void seg_starts4_kernel(
    const int4* __restrict__ ray4, int M4, int M, int N,
    const int* __restrict__ ray_id, int* __restrict__ starts)
{
    const int i = blockIdx.x * blockDim.x + threadIdx.x;
    if (i >= M4) return;
    const int4 v = ray4[i];
    const int prev = (i == 0) ? -1 : ray_id[4 * i - 1];
    const int base = 4 * i;
    for (int r = prev + 1; r <= v.x; ++r) starts[r] = base;
    for (int r = v.x + 1;  r <= v.y; ++r) starts[r] = base + 1;
    for (int r = v.y + 1;  r <= v.z; ++r) starts[r] = base + 2;
    for (int r = v.z + 1;  r <= v.w; ++r) starts[r] = base + 3;
    if (i == M4 - 1) {
        int last = v.w;
        for (int j = 4 * M4; j < M; ++j) {      // scalar tail (M%4)
            const int cur = ray_id[j];
            for (int r = last + 1; r <= cur; ++r) starts[r] = j;
            last = cur;
        }
        for (int r = last + 1; r <= N; ++r) starts[r] = M;
    }
}

// ---- Pass 2: PERSISTENT pipelined waves ------------------------------------
// R0-R8 ledger: render pinned at ~60us / 1.78 TB/s across VALU work +-33%,
// prefetch pinning, ILP depth, occupancy 42-70%, and 16B/lane dwordx4
// streams. Meanwhile the harness fill kernel sustains 6.7 TB/s on the same
// chip: its one structural difference is persistent grid-stride waves with
// continuous VMEM issue, vs our 65K one-shot burst-and-die waves (memory
// pipe drains during each wave's compute + lifecycle). This kernel adopts
// the fill's shape: 8K waves, each looping 8 ray-pairs, software-pipelined
// (issue pair i+1's 4x dwordx4 loads, sched_barrier, compute pair i).
// Per-pair math/masking/stores identical to R8's verified body.
#define WPB   4      // waves per 256-thread block
#define MAXIT 8      // ray-pairs per wave

struct Grp { float d0, d1, d2, d3; f3 c0, c1, c2, c3; };

__device__ __forceinline__ Grp load_grp_f4(
    const float* __restrict__ density, const float* __restrict__ rgb_feat,
    int s0, int s1, int s2, int t, int M)
{
    const int half = t >> 5, r = t & 31;
    const int st = half ? s1 : s0;
    const int en = half ? s2 : s1;
    const int i0 = st + 4 * r;
    int b = (i0 < en) ? i0 : en - 4;
    b = min(max(b, 0), M - 4);              // always-safe f4 base
    Grp g;
    const f4s dv = *(const f4s*)(density + b);
    const f4s q0 = *(const f4s*)(rgb_feat + 3 * b);
    const f4s q1 = *(const f4s*)(rgb_feat + 3 * b + 4);
    const f4s q2 = *(const f4s*)(rgb_feat + 3 * b + 8);
    g.d0 = dv.x; g.d1 = dv.y; g.d2 = dv.z; g.d3 = dv.w;
    g.c0 = f3{q0.x, q0.y, q0.z};
    g.c1 = f3{q0.w, q1.x, q1.y};
    g.c2 = f3{q1.z, q1.w, q2.x};
    g.c3 = f3{q2.y, q2.z, q2.w};
    return g;
}

__device__ __forceinline__ void compute_pair(
    const Grp& g, int s0, int s1, int s2, int t, int M, int N, int ray0,
    float sh,
    const float* __restrict__ density, const float* __restrict__ rgb_feat,
    float* __restrict__ weights, float* __restrict__ alphainv_last,
    float* __restrict__ out3)
{
    const int half = t >> 5, r = t & 31;
    const int st = half ? s1 : s0;
    const int en = half ? s2 : s1;
    const int len0 = s1 - s0, len1 = s2 - s1;
    const bool unsafe_tail = (s2 > M - 4);   // uniform; last pairs only
    const int i0 = st + 4 * r;

    float d0 = g.d0, d1 = g.d1, d2 = g.d2, d3 = g.d3;
    f3 c0 = g.c0, c1 = g.c1, c2 = g.c2, c3 = g.c3;
    if (unsafe_tail) {                       // redo exact (rare, uniform)
        const int k0 = max(min(i0,     en - 1), 0);
        const int k1 = max(min(i0 + 1, en - 1), 0);
        const int k2 = max(min(i0 + 2, en - 1), 0);
        const int k3 = max(min(i0 + 3, en - 1), 0);
        d0 = density[k0]; d1 = density[k1];
        d2 = density[k2]; d3 = density[k3];
        c0 = *(const f3*)(rgb_feat + 3 * k0);
        c1 = *(const f3*)(rgb_feat + 3 * k1);
        c2 = *(const f3*)(rgb_feat + 3 * k2);
        c3 = *(const f3*)(rgb_feat + 3 * k3);
    }

    float carry = 1.0f, accR = 0.0f, accG = 0.0f, accB = 0.0f;

    {   // ---- pass 0 (samples st .. st+127), from prefetched regs ----
        const bool v0 = (i0     < en), v1 = (i0 + 1 < en);
        const bool v2 = (i0 + 2 < en), v3 = (i0 + 3 < en);
        const float u0 = 1.0f + __expf(d0 + sh);
        const float u1 = 1.0f + __expf(d1 + sh);
        const float u2 = 1.0f + __expf(d2 + sh);
        const float u3 = 1.0f + __expf(d3 + sh);
        const float a0 = v0 ? __builtin_amdgcn_rsqf(u0) : 1.0f;
        const float a1 = v1 ? __builtin_amdgcn_rsqf(u1) : 1.0f;
        const float a2 = v2 ? __builtin_amdgcn_rsqf(u2) : 1.0f;
        const float a3 = v3 ? __builtin_amdgcn_rsqf(u3) : 1.0f;
        const float m = (a0 * a1) * (a2 * a3);
        const float S = half_scan_mul(m);
        float E = bperm_f((t + 63) & 63, S);
        E = (r == 0) ? 1.0f : E;
        const float tot = bperm_f(t | 31, S);
        float p = E;                          // carry==1 on pass 0
        const float w0 = p * (1.0f - a0); p *= a0;
        const float w1 = p * (1.0f - a1); p *= a1;
        const float w2 = p * (1.0f - a2); p *= a2;
        const float w3 = p * (1.0f - a3);
        accR = w0 * fast_sigmoid(c0.x) + w1 * fast_sigmoid(c1.x)
             + w2 * fast_sigmoid(c2.x) + w3 * fast_sigmoid(c3.x);
        accG = w0 * fast_sigmoid(c0.y) + w1 * fast_sigmoid(c1.y)
             + w2 * fast_sigmoid(c2.y) + w3 * fast_sigmoid(c3.y);
        accB = w0 * fast_sigmoid(c0.z) + w1 * fast_sigmoid(c1.z)
             + w2 * fast_sigmoid(c2.z) + w3 * fast_sigmoid(c3.z);
        if (v3) {
            f4s wv; wv.x = w0; wv.y = w1; wv.z = w2; wv.w = w3;
            *(f4s*)(weights + i0) = wv;
        } else {
            if (v0) weights[i0]     = w0;
            if (v1) weights[i0 + 1] = w1;
            if (v2) weights[i0 + 2] = w2;
        }
        carry = tot;
    }

    // ---- rare extra passes (len > 128; ~never on this data) ----
    int off = 128;
    while (len0 > off || len1 > off) {       // uniform condition
        const int ii = st + off + 4 * r;
        const int k0 = max(min(ii,     en - 1), 0);
        const int k1 = max(min(ii + 1, en - 1), 0);
        const int k2 = max(min(ii + 2, en - 1), 0);
        const int k3 = max(min(ii + 3, en - 1), 0);
        const float e0 = density[k0], e1 = density[k1];
        const float e2 = density[k2], e3 = density[k3];
        const f3 x0 = *(const f3*)(rgb_feat + 3 * k0);
        const f3 x1 = *(const f3*)(rgb_feat + 3 * k1);
        const f3 x2 = *(const f3*)(rgb_feat + 3 * k2);
        const f3 x3 = *(const f3*)(rgb_feat + 3 * k3);
        const bool v0 = (ii     < en), v1 = (ii + 1 < en);
        const bool v2 = (ii + 2 < en), v3 = (ii + 3 < en);
        const float u0 = 1.0f + __expf(e0 + sh);
        const float u1 = 1.0f + __expf(e1 + sh);
        const float u2 = 1.0f + __expf(e2 + sh);
        const float u3 = 1.0f + __expf(e3 + sh);
        const float a0 = v0 ? __builtin_amdgcn_rsqf(u0) : 1.0f;
        const float a1 = v1 ? __builtin_amdgcn_rsqf(u1) : 1.0f;
        const float a2 = v2 ? __builtin_amdgcn_rsqf(u2) : 1.0f;
        const float a3 = v3 ? __builtin_amdgcn_rsqf(u3) : 1.0f;
        const float m = (a0 * a1) * (a2 * a3);
        const float S = half_scan_mul(m);
        float E = bperm_f((t + 63) & 63, S);
        E = (r == 0) ? 1.0f : E;
        const float tot = bperm_f(t | 31, S);
        float p = carry * E;
        const float w0 = p * (1.0f - a0); p *= a0;
        const float w1 = p * (1.0f - a1); p *= a1;
        const float w2 = p * (1.0f - a2); p *= a2;
        const float w3 = p * (1.0f - a3);
        accR += w0 * fast_sigmoid(x0.x) + w1 * fast_sigmoid(x1.x)
              + w2 * fast_sigmoid(x2.x) + w3 * fast_sigmoid(x3.x);
        accG += w0 * fast_sigmoid(x0.y) + w1 * fast_sigmoid(x1.y)
              + w2 * fast_sigmoid(x2.y) + w3 * fast_sigmoid(x3.y);
        accB += w0 * fast_sigmoid(x0.z) + w1 * fast_sigmoid(x1.z)
              + w2 * fast_sigmoid(x2.z) + w3 * fast_sigmoid(x3.z);
        if (v0) weights[ii]     = w0;
        if (v1) weights[ii + 1] = w1;
        if (v2) weights[ii + 2] = w2;
        if (v3) weights[ii + 3] = w3;
        carry *= tot;
        off += 128;
    }

    // ---- epilogue: 3 half-scan-adds cover BOTH rays at once ----
    accR = half_scan_add(accR);
    accG = half_scan_add(accG);
    accB = half_scan_add(accB);
    if ((t & 31) == 31) {                    // lane 31 -> ray0, 63 -> ray0+1
        const int ray = ray0 + half;
        if (ray < N) {
            alphainv_last[ray] = carry;
            f3 o;
            o.x = accR + carry; o.y = accG + carry; o.z = accB + carry;
            *(f3*)(out3 + 3 * ray) = o;
        }
    }
}

__global__ __launch_bounds__(256, 4) void favor_render_kernel(
    const float* __restrict__ density,
    const float* __restrict__ rgb_feat,   // [M,3]
    const float* __restrict__ shift,      // [1]
    const int*   __restrict__ starts,     // [N+1]
    int M, int N,
    float* __restrict__ weights,          // [M]
    float* __restrict__ alphainv_last,    // [N]
    float* __restrict__ out3)             // [N,3]
{
    const int wid = (blockIdx.x * blockDim.x + threadIdx.x) >> 6;
    const int t   = threadIdx.x & 63;
    const int NW  = gridDim.x * (blockDim.x >> 6);   // total waves

    // Boundary table for all MAXIT iterations: one coalesced-ish load,
    // 3 values per iteration, broadcast via readlane (lanes >= 3*MAXIT
    // read starts[N]=M harmlessly).
    int bidx = N;
    if (t < 3 * MAXIT) {
        const int itq = t / 3, c = t - 3 * itq;
        const int pr  = wid + itq * NW;
        bidx = min(N, 2 * pr + c);
    }
    const int bv = starts[bidx];
    const float sh = shift[0];

    // Prologue: prefetch iteration 0.
    Grp cur = load_grp_f4(density, rgb_feat,
                          rdlane(bv, 0), rdlane(bv, 1), rdlane(bv, 2), t, M);

    #pragma unroll
    for (int it = 0; it < MAXIT; ++it) {
        const int s0 = rdlane(bv, 3 * it + 0);
        const int s1 = rdlane(bv, 3 * it + 1);
        const int s2 = rdlane(bv, 3 * it + 2);
        const int pr = wid + it * NW;

        Grp nxt;
        if (it + 1 < MAXIT) {               // issue next pair's loads NOW
            nxt = load_grp_f4(density, rgb_feat,
                              rdlane(bv, 3 * it + 3),
                              rdlane(bv, 3 * it + 4),
                              rdlane(bv, 3 * it + 5), t, M);
        }
        // Compile-time fence: next-pair loads cannot be sunk below the
        // compute; their waitcnt lands at first use (next iteration).
        __builtin_amdgcn_sched_barrier(0);

        if (2 * pr < N) {
            compute_pair(cur, s0, s1, s2, t, M, N, 2 * pr, sh,
                         density, rgb_feat, weights, alphainv_last, out3);
        }
        cur = nxt;
    }
}

extern "C" void kernel_launch(void* const* d_in, const int* in_sizes, int n_in,
                              void* d_out, int out_size, void* d_ws, size_t ws_size,
                              hipStream_t stream) {
    const float* density  = (const float*)d_in[0];
    const float* rgb_feat = (const float*)d_in[1];
    const float* shift    = (const float*)d_in[2];
    const int*   ray_id   = (const int*)d_in[3];

    const int M = in_sizes[0];
    const int N = (out_size - M) / 4;   // out_size = M + N + 3N

    float* weights       = (float*)d_out;
    float* alphainv_last = weights + M;
    float* out3          = alphainv_last + N;

    const int block = 256;
    int* starts = (int*)d_ws;

    const int M4 = M >> 2;
    const int grid_starts = (M4 + block - 1) / block;
    seg_starts4_kernel<<<grid_starts, block, 0, stream>>>(
        (const int4*)ray_id, M4, M, N, ray_id, starts);

    // Persistent waves: each handles MAXIT ray-pairs.
    const int npairs  = (N + 1) / 2;
    const int n_waves = (npairs + MAXIT - 1) / MAXIT;
    const int grid_render = (n_waves * 64 + block - 1) / block;
    favor_render_kernel<<<grid_render, block, 0, stream>>>(
        density, rgb_feat, shift, starts, M, N,
        weights, alphainv_last, out3);
}

// Round 10
// 209.971 us; speedup vs baseline: 1.0388x; 1.0388x over previous
//
#include <hip/hip_runtime.h>

// 1 - alpha = (1 + exp(density+shift))^(-0.5) = rsqrt(u), u = 1 + exp(x).
// w_k = T_excl * alpha_k,  T_excl accumulated as product of (1-alpha).

__device__ __forceinline__ float fast_sigmoid(float x) {
    return __builtin_amdgcn_rcpf(1.0f + __expf(-x));
}

struct __align__(4) f3  { float x, y, z; };     // 12B, 4B-aligned
// 16B vector with 4B alignment: weights/density/rgb addresses are only
// dword-aligned (st is arbitrary); gfx9 global dwordx4 needs dword align.
typedef float f4v __attribute__((ext_vector_type(4), aligned(4)));

// ---- DPP wave64 scans ------------------------------------------------------
#define DPP_ADD(x, ctrl, rmask)                                               \
    do {                                                                      \
        int _s = __builtin_amdgcn_update_dpp(0, __float_as_int(x), (ctrl),    \
                                             (rmask), 0xf, true);             \
        (x) += __int_as_float(_s);                                            \
    } while (0)

#define DPP_MUL(x, ctrl, rmask)                                               \
    do {                                                                      \
        int _s = __builtin_amdgcn_update_dpp(0x3f800000, __float_as_int(x),   \
                                             (ctrl), (rmask), 0xf, false);    \
        (x) *= __int_as_float(_s);                                            \
    } while (0)

// Inclusive scans SEGMENTED at the lane-31/32 boundary (R3/R8-verified):
// stages row_shr:1/2/4/8 + row_bcast:15 (rows 1,3) never cross 32-lane halves.
__device__ __forceinline__ float half_scan_mul(float x) {
    DPP_MUL(x, 0x111, 0xf);
    DPP_MUL(x, 0x112, 0xf);
    DPP_MUL(x, 0x114, 0xf);
    DPP_MUL(x, 0x118, 0xf);
    DPP_MUL(x, 0x142, 0xa);
    return x;
}
__device__ __forceinline__ float half_scan_add(float x) {
    DPP_ADD(x, 0x111, 0xf);
    DPP_ADD(x, 0x112, 0xf);
    DPP_ADD(x, 0x114, 0xf);
    DPP_ADD(x, 0x118, 0xf);
    DPP_ADD(x, 0x142, 0xa);
    return x;
}

__device__ __forceinline__ float bperm_f(int lane, float v) {
    return __int_as_float(
        __builtin_amdgcn_ds_bpermute(lane * 4, __float_as_int(v)));
}

// ---- Pass 1: segment starts (int4-vectorized boundary detection) -----------
__global__ __launch_bounds__(256) void seg_starts4_kernel(
    const int4* __restrict__ ray4, int M4, int M, int N,
    const int* __restrict__ ray_id, int* __restrict__ starts)
{
    const int i = blockIdx.x * blockDim.x + threadIdx.x;
    if (i >= M4) return;
    const int4 v = ray4[i];
    const int prev = (i == 0) ? -1 : ray_id[4 * i - 1];
    const int base = 4 * i;
    for (int r = prev + 1; r <= v.x; ++r) starts[r] = base;
    for (int r = v.x + 1;  r <= v.y; ++r) starts[r] = base + 1;
    for (int r = v.y + 1;  r <= v.z; ++r) starts[r] = base + 2;
    for (int r = v.z + 1;  r <= v.w; ++r) starts[r] = base + 3;
    if (i == M4 - 1) {
        int last = v.w;
        for (int j = 4 * M4; j < M; ++j) {      // scalar tail (M%4)
            const int cur = ray_id[j];
            for (int r = last + 1; r <= cur; ++r) starts[r] = j;
            last = cur;
        }
        for (int r = last + 1; r <= N; ++r) starts[r] = M;
    }
}

// ---- Pass 2: ray = 32-lane half, 4 samples/lane, NONTEMPORAL streams -------
// R0-R9 ledger: render pinned at ~60us across VALU work +-33%, prefetch
// pinning, ILP depth, dwordx4 width, persistence; ONLY reducing TLP ever
// hurt -> latency-bound at max occupancy. Remaining lever: the loads'
// latency itself. density/rgb are 134 MB of SINGLE-USE streaming reads that
// continuously flush the 32MB L2, evicting the highly-reused 0.5MB `starts`
// table (every wave's dependent first load) and forcing read misses;
// weights stores (34MB) write-allocate more pollution. Fix: nontemporal
// loads for density/rgb, nontemporal stores for weights; `starts` and
// outputs stay cached. Structure otherwise identical to R8 (verified).
#define RPW 2

__global__ __launch_bounds__(256, 4) void favor_render_kernel(
    const float* __restrict__ density,
    const float* __restrict__ rgb_feat,   // [M,3]
    const float* __restrict__ shift,      // [1]
    const int*   __restrict__ starts,     // [N+1]
    int M, int N,
    float* __restrict__ weights,          // [M]
    float* __restrict__ alphainv_last,    // [N]
    float* __restrict__ out3)             // [N,3]
{
    const int wave = (blockIdx.x * blockDim.x + threadIdx.x) >> 6;
    const int t    = threadIdx.x & 63;
    const int r0   = wave * RPW;
    if (r0 >= N) return;

    const int bv = starts[min(r0 + t, N)];
    const int s0 = __builtin_amdgcn_readlane(bv, 0);
    const int s1 = __builtin_amdgcn_readlane(bv, 1);
    const int s2 = __builtin_amdgcn_readlane(bv, 2);

    const int  half = t >> 5;            // 0: ray r0, 1: ray r0+1
    const int  r    = t & 31;
    const int  st   = half ? s1 : s0;
    const int  en   = half ? s2 : s1;
    const int  len0 = s1 - s0, len1 = s2 - s1;

    const float sh = shift[0];
    // Uniform (scalar) guard: only the last wave(s) can have f4 reads that
    // run past the end of density/rgb_feat; they take per-sample clamped loads.
    const bool unsafe_tail = (s2 > M - 4);

    float carry = 1.0f, accR = 0.0f, accG = 0.0f, accB = 0.0f;
    int off = 0;

    do {
        const int i0 = st + off + 4 * r;

        float d0, d1, d2, d3;
        f3 c0, c1, c2, c3;
        if (unsafe_tail) {                       // last wave only (cached path)
            const int k0 = max(min(i0,     en - 1), 0);
            const int k1 = max(min(i0 + 1, en - 1), 0);
            const int k2 = max(min(i0 + 2, en - 1), 0);
            const int k3 = max(min(i0 + 3, en - 1), 0);
            d0 = density[k0]; d1 = density[k1];
            d2 = density[k2]; d3 = density[k3];
            c0 = *(const f3*)(rgb_feat + 3 * k0);
            c1 = *(const f3*)(rgb_feat + 3 * k1);
            c2 = *(const f3*)(rgb_feat + 3 * k2);
            c3 = *(const f3*)(rgb_feat + 3 * k3);
        } else {
            // Fully-invalid lanes clamp the base (values masked later);
            // partially-valid lanes load at i0 (reads spill into the next
            // ray's region: in-bounds, masked). Safe: en <= M-4 here.
            // NONTEMPORAL: single-use stream, keep L2 for `starts`.
            const int b  = (i0 < en) ? i0 : max(en - 4, 0);
            const f4v dv = __builtin_nontemporal_load((const f4v*)(density + b));
            const f4v q0 = __builtin_nontemporal_load((const f4v*)(rgb_feat + 3 * b));
            const f4v q1 = __builtin_nontemporal_load((const f4v*)(rgb_feat + 3 * b + 4));
            const f4v q2 = __builtin_nontemporal_load((const f4v*)(rgb_feat + 3 * b + 8));
            d0 = dv.x; d1 = dv.y; d2 = dv.z; d3 = dv.w;
            c0.x = q0.x; c0.y = q0.y; c0.z = q0.z;
            c1.x = q0.w; c1.y = q1.x; c1.z = q1.y;
            c2.x = q1.z; c2.y = q1.w; c2.z = q2.x;
            c3.x = q2.y; c3.y = q2.z; c3.z = q2.w;
        }

        const bool v0 = (i0     < en), v1 = (i0 + 1 < en);
        const bool v2 = (i0 + 2 < en), v3 = (i0 + 3 < en);

        const float u0 = 1.0f + __expf(d0 + sh);
        const float u1 = 1.0f + __expf(d1 + sh);
        const float u2 = 1.0f + __expf(d2 + sh);
        const float u3 = 1.0f + __expf(d3 + sh);
        const float a0 = v0 ? __builtin_amdgcn_rsqf(u0) : 1.0f;
        const float a1 = v1 ? __builtin_amdgcn_rsqf(u1) : 1.0f;
        const float a2 = v2 ? __builtin_amdgcn_rsqf(u2) : 1.0f;
        const float a3 = v3 ? __builtin_amdgcn_rsqf(u3) : 1.0f;

        const float m = (a0 * a1) * (a2 * a3);   // lane's 4-sample product
        const float S = half_scan_mul(m);        // inclusive over 32-lane half
        float E = bperm_f((t + 63) & 63, S);     // previous lane's inclusive
        E = (r == 0) ? 1.0f : E;                 // half-head identity
        const float tot = bperm_f(t | 31, S);    // half total -> all lanes

        float p = carry * E;                     // T before sample i0
        const float w0 = p * (1.0f - a0); p *= a0;
        const float w1 = p * (1.0f - a1); p *= a1;
        const float w2 = p * (1.0f - a2); p *= a2;
        const float w3 = p * (1.0f - a3);

        accR += w0 * fast_sigmoid(c0.x) + w1 * fast_sigmoid(c1.x)
              + w2 * fast_sigmoid(c2.x) + w3 * fast_sigmoid(c3.x);
        accG += w0 * fast_sigmoid(c0.y) + w1 * fast_sigmoid(c1.y)
              + w2 * fast_sigmoid(c2.y) + w3 * fast_sigmoid(c3.y);
        accB += w0 * fast_sigmoid(c0.z) + w1 * fast_sigmoid(c1.z)
              + w2 * fast_sigmoid(c2.z) + w3 * fast_sigmoid(c3.z);

        if (v3) {                                // all 4 valid: one NT dwordx4
            f4v wv; wv.x = w0; wv.y = w1; wv.z = w2; wv.w = w3;
            __builtin_nontemporal_store(wv, (f4v*)(weights + i0));
        } else {                                 // boundary lane of the ray
            if (v0) __builtin_nontemporal_store(w0, weights + i0);
            if (v1) __builtin_nontemporal_store(w1, weights + i0 + 1);
            if (v2) __builtin_nontemporal_store(w2, weights + i0 + 2);
        }

        carry *= tot;
        off += 128;
    } while (len0 > off || len1 > off);          // uniform; ~never loops

    // ---- epilogue: 3 half-scan-adds cover BOTH rays at once ----
    accR = half_scan_add(accR);
    accG = half_scan_add(accG);
    accB = half_scan_add(accB);
    if ((t & 31) == 31) {                        // lane 31 -> ray r0, 63 -> r0+1
        const int ray = r0 + half;
        if (ray < N) {
            alphainv_last[ray] = carry;
            f3 o;
            o.x = accR + carry; o.y = accG + carry; o.z = accB + carry;
            *(f3*)(out3 + 3 * ray) = o;
        }
    }
}

extern "C" void kernel_launch(void* const* d_in, const int* in_sizes, int n_in,
                              void* d_out, int out_size, void* d_ws, size_t ws_size,
                              hipStream_t stream) {
    const float* density  = (const float*)d_in[0];
    const float* rgb_feat = (const float*)d_in[1];
    const float* shift    = (const float*)d_in[2];
    const int*   ray_id   = (const int*)d_in[3];

    const int M = in_sizes[0];
    const int N = (out_size - M) / 4;   // out_size = M + N + 3N

    float* weights       = (float*)d_out;
    float* alphainv_last = weights + M;
    float* out3          = alphainv_last + N;

    const int block = 256;
    int* starts = (int*)d_ws;

    const int M4 = M >> 2;
    const int grid_starts = (M4 + block - 1) / block;
    seg_starts4_kernel<<<grid_starts, block, 0, stream>>>(
        (const int4*)ray_id, M4, M, N, ray_id, starts);

    const int n_waves = (N + RPW - 1) / RPW;
    const int grid_render = (n_waves * 64 + block - 1) / block;
    favor_render_kernel<<<grid_render, block, 0, stream>>>(
        density, rgb_feat, shift, starts, M, N,
        weights, alphainv_last, out3);
}